// Round 1
// baseline (109.375 us; speedup 1.0000x reference)
//
#include <hip/hip_runtime.h>

// Problem constants (from reference): x is (64, 65536) fp32.
#define L_LEN  65536
#define B_ROWS 64
#define NF     32            // conv filters
#define SLICES 32            // slices per row (pass-1 grid.y)
#define TPB    256
#define CHUNK  (L_LEN / SLICES)   // 2048 elements per block
#define EPT    (CHUNK / TPB)      // 8 elements per thread
#define NV     36                 // partial values: sum, sumsq, max, min, 32 filter maxes

// -------------------- Pass 1: stats + conv-max partials --------------------
// deep[f] = max_l relu(conv_raw[f][l] + b[f]) = relu(max_l conv_raw + b[f]);
// bias+relu deferred to pass 2, so the hot loop is 3 FMA + 1 max per (f, l).
__global__ __launch_bounds__(TPB) void fp_pass1(
    const float* __restrict__ x, const float* __restrict__ cw,
    float* __restrict__ ws)
{
    const int row   = blockIdx.x;
    const int slice = blockIdx.y;
    const float* xr = x + (size_t)row * L_LEN;
    const int base  = slice * CHUNK + (int)threadIdx.x * EPT;

    // xv[0] = x[base-1] (0 at row start), xv[1..8] = x[base..base+7],
    // xv[9] = x[base+8] (0 at row end)
    float xv[EPT + 2];
    const float4* p = reinterpret_cast<const float4*>(xr + base);
    float4 a = p[0];
    float4 b = p[1];
    xv[1] = a.x; xv[2] = a.y; xv[3] = a.z; xv[4] = a.w;
    xv[5] = b.x; xv[6] = b.y; xv[7] = b.z; xv[8] = b.w;
    xv[0]       = (base == 0)            ? 0.0f : xr[base - 1];
    xv[EPT + 1] = (base + EPT == L_LEN)  ? 0.0f : xr[base + EPT];

    // scalar stats
    float s = 0.0f, ss = 0.0f;
    float mx = -3.4e38f, mn = 3.4e38f;
#pragma unroll
    for (int j = 1; j <= EPT; ++j) {
        const float v = xv[j];
        s += v;
        ss = fmaf(v, v, ss);
        mx = fmaxf(mx, v);
        mn = fminf(mn, v);
    }

    // conv-max per filter (raw conv, no bias/relu here)
    float m[NF];
#pragma unroll
    for (int f = 0; f < NF; ++f) {
        const float w0 = cw[3 * f + 0];
        const float w1 = cw[3 * f + 1];
        const float w2 = cw[3 * f + 2];
        float best0 = -3.4e38f, best1 = -3.4e38f;   // two chains for ILP
#pragma unroll
        for (int j = 0; j < EPT; j += 2) {
            const float c0 = fmaf(w0, xv[j],     fmaf(w1, xv[j + 1], w2 * xv[j + 2]));
            const float c1 = fmaf(w0, xv[j + 1], fmaf(w1, xv[j + 2], w2 * xv[j + 3]));
            best0 = fmaxf(best0, c0);
            best1 = fmaxf(best1, c1);
        }
        m[f] = fmaxf(best0, best1);
    }

    // wave(64) butterfly reduction of all 36 values
#pragma unroll
    for (int off = 32; off > 0; off >>= 1) {
        s  += __shfl_xor(s,  off, 64);
        ss += __shfl_xor(ss, off, 64);
        mx  = fmaxf(mx, __shfl_xor(mx, off, 64));
        mn  = fminf(mn, __shfl_xor(mn, off, 64));
#pragma unroll
        for (int f = 0; f < NF; ++f)
            m[f] = fmaxf(m[f], __shfl_xor(m[f], off, 64));
    }

    // cross-wave (4 waves) via LDS, then one store per value
    __shared__ float red[TPB / 64][NV];
    const int wid  = threadIdx.x >> 6;
    const int lane = threadIdx.x & 63;
    if (lane == 0) {
        red[wid][0] = s; red[wid][1] = ss; red[wid][2] = mx; red[wid][3] = mn;
#pragma unroll
        for (int f = 0; f < NF; ++f) red[wid][4 + f] = m[f];
    }
    __syncthreads();
    if (threadIdx.x < NV) {
        const int v = threadIdx.x;
        float r;
        if (v < 2)
            r = (red[0][v] + red[1][v]) + (red[2][v] + red[3][v]);
        else if (v == 3)
            r = fminf(fminf(red[0][v], red[1][v]), fminf(red[2][v], red[3][v]));
        else
            r = fmaxf(fmaxf(red[0][v], red[1][v]), fmaxf(red[2][v], red[3][v]));
        ws[((size_t)row * SLICES + slice) * NV + v] = r;
    }
}

// -------------------- Pass 2: slice reduction + MLP --------------------
__global__ __launch_bounds__(64) void fp_pass2(
    const float* __restrict__ ws, const float* __restrict__ cb,
    const float* __restrict__ w1, const float* __restrict__ b1,
    const float* __restrict__ w2, const float* __restrict__ b2,
    const float* __restrict__ w3, const float* __restrict__ b3,
    const float* __restrict__ w4, const float* __restrict__ b4,
    float* __restrict__ out)
{
    const int row = blockIdx.x;
    const int t   = (int)threadIdx.x;
    __shared__ float feat[NV];
    __shared__ float h1[64];
    __shared__ float h2[32];
    __shared__ float h3[16];

    if (t < NV) {
        const float* p = ws + (size_t)row * SLICES * NV + t;
        float r = p[0];
        if (t < 2) {
            for (int sl = 1; sl < SLICES; ++sl) r += p[sl * NV];
        } else if (t == 3) {
            for (int sl = 1; sl < SLICES; ++sl) r = fminf(r, p[sl * NV]);
        } else {
            for (int sl = 1; sl < SLICES; ++sl) r = fmaxf(r, p[sl * NV]);
        }
        if (t >= 4)       feat[t - 4] = fmaxf(r + cb[t - 4], 0.0f); // deep: relu(max+b)
        else if (t == 2)  feat[34] = r;                              // max
        else if (t == 3)  feat[35] = r;                              // min
        else              feat[32 + t] = r;                          // raw sum / sumsq
    }
    __syncthreads();
    if (t == 0) {
        const float inv = 1.0f / (float)L_LEN;
        const float mean = feat[32] * inv;
        const float var  = feat[33] * inv - mean * mean;
        feat[32] = mean;
        feat[33] = var;
    }
    __syncthreads();

    // layer 1: (36) -> (64), w1 row-major (36,64)
    {
        float acc = b1[t];
        for (int i = 0; i < NV; ++i) acc = fmaf(feat[i], w1[i * 64 + t], acc);
        h1[t] = fmaxf(acc, 0.0f);
    }
    __syncthreads();
    // layer 2: (64) -> (32)
    if (t < 32) {
        float acc = b2[t];
        for (int i = 0; i < 64; ++i) acc = fmaf(h1[i], w2[i * 32 + t], acc);
        h2[t] = fmaxf(acc, 0.0f);
    }
    __syncthreads();
    // layer 3: (32) -> (16)
    if (t < 16) {
        float acc = b3[t];
        for (int i = 0; i < 32; ++i) acc = fmaf(h2[i], w3[i * 16 + t], acc);
        h3[t] = fmaxf(acc, 0.0f);
    }
    __syncthreads();
    // layer 4: (16) -> (2)
    if (t < 2) {
        float acc = b4[t];
        for (int i = 0; i < 16; ++i) acc = fmaf(h3[i], w4[i * 2 + t], acc);
        out[row * 2 + t] = acc;
    }
}

extern "C" void kernel_launch(void* const* d_in, const int* in_sizes, int n_in,
                              void* d_out, int out_size, void* d_ws, size_t ws_size,
                              hipStream_t stream) {
    const float* x  = (const float*)d_in[0];
    const float* cw = (const float*)d_in[1];
    const float* cb = (const float*)d_in[2];
    const float* w1 = (const float*)d_in[3];
    const float* b1 = (const float*)d_in[4];
    const float* w2 = (const float*)d_in[5];
    const float* b2 = (const float*)d_in[6];
    const float* w3 = (const float*)d_in[7];
    const float* b3 = (const float*)d_in[8];
    const float* w4 = (const float*)d_in[9];
    const float* b4 = (const float*)d_in[10];
    float* out = (float*)d_out;
    float* ws  = (float*)d_ws;   // needs 64*32*36*4 = 294912 bytes

    dim3 g1(B_ROWS, SLICES);
    fp_pass1<<<g1, TPB, 0, stream>>>(x, cw, ws);
    fp_pass2<<<B_ROWS, 64, 0, stream>>>(ws, cb, w1, b1, w2, b2, w3, b3, w4, b4, out);
}

// Round 2
// 95.329 us; speedup vs baseline: 1.1473x; 1.1473x over previous
//
#include <hip/hip_runtime.h>

// x is (64, 65536) fp32.
#define L_LEN  65536
#define B_ROWS 64
#define NF     32                 // conv filters
#define SLICES 16                 // slices per row (pass-1 grid.y)
#define TPB    256
#define CHUNK  (L_LEN / SLICES)   // 4096 elements per block
#define EPT    (CHUNK / TPB)      // 16 elements per thread
#define NV     36                 // sum, sumsq, max, min, 32 filter maxes
#define PAD    37                 // LDS row pad (37 odd -> conflict-free writes)

typedef float f2 __attribute__((ext_vector_type(2)));

// -------------------- Pass 1: stats + conv-max partials --------------------
// deep[f] = max_l relu(conv_raw + b[f]) = relu(max_l conv_raw + b[f]);
// bias+relu deferred to pass 2. Conv uses packed fp32 (v_pk_fma_f32):
// outputs (c[2i], c[2i+1]) = w0*{x[2i-1],x[2i]} + w1*{x[2i],x[2i+1]} + w2*{x[2i+1],x[2i+2]}
__global__ __launch_bounds__(TPB) void fp_pass1(
    const float* __restrict__ x, const float* __restrict__ cw,
    float* __restrict__ ws)
{
    const int row   = blockIdx.x;
    const int slice = blockIdx.y;
    const int t     = (int)threadIdx.x;
    const float* xr = x + (size_t)row * L_LEN;
    const int base  = slice * CHUNK + t * EPT;

    // xv[k] = x[base + k - 1]; xv[0]/xv[17] are halo (0 at row edges)
    float xv[EPT + 2];
    const float4* p = reinterpret_cast<const float4*>(xr + base);
    float4 a0 = p[0], a1 = p[1], a2 = p[2], a3 = p[3];
    xv[1]  = a0.x; xv[2]  = a0.y; xv[3]  = a0.z; xv[4]  = a0.w;
    xv[5]  = a1.x; xv[6]  = a1.y; xv[7]  = a1.z; xv[8]  = a1.w;
    xv[9]  = a2.x; xv[10] = a2.y; xv[11] = a2.z; xv[12] = a2.w;
    xv[13] = a3.x; xv[14] = a3.y; xv[15] = a3.z; xv[16] = a3.w;
    xv[0]           = (base == 0)           ? 0.0f : xr[base - 1];
    xv[EPT + 1]     = (base + EPT == L_LEN) ? 0.0f : xr[base + EPT];

    // Packed windows: ev[i] = {xv[2i], xv[2i+1]}, od[i] = {xv[2i+1], xv[2i+2]}
    f2 ev[EPT / 2 + 1], od[EPT / 2];
#pragma unroll
    for (int i = 0; i <= EPT / 2; ++i) ev[i] = f2{xv[2 * i], xv[2 * i + 1]};
#pragma unroll
    for (int i = 0; i < EPT / 2; ++i)  od[i] = f2{xv[2 * i + 1], xv[2 * i + 2]};

    // stats over xv[1..16] (== all od[] lanes)
    f2 s2 = f2{0.0f, 0.0f}, ss2 = f2{0.0f, 0.0f};
#pragma unroll
    for (int i = 0; i < EPT / 2; ++i) {
        s2 += od[i];
        ss2 = __builtin_elementwise_fma(od[i], od[i], ss2);
    }
    float s  = s2.x + s2.y;
    float ss = ss2.x + ss2.y;
    float mx = xv[1], mn = xv[1];
#pragma unroll
    for (int j = 2; j <= EPT; ++j) {
        mx = fmaxf(mx, xv[j]);
        mn = fminf(mn, xv[j]);
    }

    // conv-max per filter (raw conv; packed fp32 FMAs + max3 folding)
    float m[NF];
#pragma unroll
    for (int f = 0; f < NF; ++f) {
        const f2 w0 = f2{cw[3 * f + 0], cw[3 * f + 0]};
        const f2 w1 = f2{cw[3 * f + 1], cw[3 * f + 1]};
        const f2 w2 = f2{cw[3 * f + 2], cw[3 * f + 2]};
        float best0 = -3.4e38f, best1 = -3.4e38f;   // two chains for ILP
#pragma unroll
        for (int i = 0; i < EPT / 2; i += 2) {
            f2 c0 = __builtin_elementwise_fma(w0, ev[i],
                     __builtin_elementwise_fma(w1, od[i], w2 * ev[i + 1]));
            f2 c1 = __builtin_elementwise_fma(w0, ev[i + 1],
                     __builtin_elementwise_fma(w1, od[i + 1], w2 * ev[i + 2]));
            best0 = fmaxf(best0, fmaxf(c0.x, c0.y));   // -> v_max3
            best1 = fmaxf(best1, fmaxf(c1.x, c1.y));
        }
        m[f] = fmaxf(best0, best1);
    }

    // ---- block reduction via LDS matrix transpose ----
    __shared__ float mred[TPB * PAD];
    float* myrow = &mred[t * PAD];
    myrow[0] = s; myrow[1] = ss; myrow[2] = mx; myrow[3] = mn;
#pragma unroll
    for (int f = 0; f < NF; ++f) myrow[4 + f] = m[f];
    __syncthreads();

    if (t < NV * 4) {            // 144 reducer threads: v = value, g = quarter
        const int v = t >> 2, g = t & 3;
        float rs = 0.0f, rmx = -3.4e38f, rmn = 3.4e38f;
        for (int k = 0; k < TPB / 4; ++k) {
            const float val = mred[(g + 4 * k) * PAD + v];
            rs += val;
            rmx = fmaxf(rmx, val);
            rmn = fminf(rmn, val);
        }
        float r = (v < 2) ? rs : ((v == 3) ? rmn : rmx);
        // combine the 4 quarters (lanes 4v..4v+3 are adjacent, all active)
        float o = __shfl_xor(r, 1, 64);
        r = (v < 2) ? r + o : ((v == 3) ? fminf(r, o) : fmaxf(r, o));
        o = __shfl_xor(r, 2, 64);
        r = (v < 2) ? r + o : ((v == 3) ? fminf(r, o) : fmaxf(r, o));
        if (g == 0)
            ws[((size_t)(row * SLICES + slice)) * NV + v] = r;
    }
}

// -------------------- Pass 2: slice reduction + MLP --------------------
__global__ __launch_bounds__(64) void fp_pass2(
    const float* __restrict__ ws, const float* __restrict__ cb,
    const float* __restrict__ w1, const float* __restrict__ b1,
    const float* __restrict__ w2, const float* __restrict__ b2,
    const float* __restrict__ w3, const float* __restrict__ b3,
    const float* __restrict__ w4, const float* __restrict__ b4,
    float* __restrict__ out)
{
    const int row = blockIdx.x;
    const int t   = (int)threadIdx.x;
    __shared__ float feat[NV];
    __shared__ float h1[64];
    __shared__ float h2[32];
    __shared__ float h3[16];

    if (t < NV) {
        const float* p = ws + (size_t)row * SLICES * NV + t;
        float rs = 0.0f, rmx = -3.4e38f, rmn = 3.4e38f;
        for (int sl = 0; sl < SLICES; ++sl) {
            const float val = p[sl * NV];
            rs += val;
            rmx = fmaxf(rmx, val);
            rmn = fminf(rmn, val);
        }
        const float r = (t < 2) ? rs : ((t == 3) ? rmn : rmx);
        if (t >= 4)       feat[t - 4] = fmaxf(r + cb[t - 4], 0.0f); // deep
        else if (t == 2)  feat[34] = r;                              // max
        else if (t == 3)  feat[35] = r;                              // min
        else              feat[32 + t] = r;                          // raw sums
    }
    __syncthreads();
    if (t == 0) {
        const float inv  = 1.0f / (float)L_LEN;
        const float mean = feat[32] * inv;
        const float var  = feat[33] * inv - mean * mean;
        feat[32] = mean;
        feat[33] = var;
    }
    __syncthreads();

    // layer 1: (36) -> (64)
    {
        float acc = b1[t];
        for (int i = 0; i < NV; ++i) acc = fmaf(feat[i], w1[i * 64 + t], acc);
        h1[t] = fmaxf(acc, 0.0f);
    }
    __syncthreads();
    // layer 2: (64) -> (32)
    if (t < 32) {
        float acc = b2[t];
        for (int i = 0; i < 64; ++i) acc = fmaf(h1[i], w2[i * 32 + t], acc);
        h2[t] = fmaxf(acc, 0.0f);
    }
    __syncthreads();
    // layer 3: (32) -> (16)
    if (t < 16) {
        float acc = b3[t];
        for (int i = 0; i < 32; ++i) acc = fmaf(h2[i], w3[i * 16 + t], acc);
        h3[t] = fmaxf(acc, 0.0f);
    }
    __syncthreads();
    // layer 4: (16) -> (2)
    if (t < 2) {
        float acc = b4[t];
        for (int i = 0; i < 16; ++i) acc = fmaf(h3[i], w4[i * 2 + t], acc);
        out[row * 2 + t] = acc;
    }
}

extern "C" void kernel_launch(void* const* d_in, const int* in_sizes, int n_in,
                              void* d_out, int out_size, void* d_ws, size_t ws_size,
                              hipStream_t stream) {
    const float* x  = (const float*)d_in[0];
    const float* cw = (const float*)d_in[1];
    const float* cb = (const float*)d_in[2];
    const float* w1 = (const float*)d_in[3];
    const float* b1 = (const float*)d_in[4];
    const float* w2 = (const float*)d_in[5];
    const float* b2 = (const float*)d_in[6];
    const float* w3 = (const float*)d_in[7];
    const float* b3 = (const float*)d_in[8];
    const float* w4 = (const float*)d_in[9];
    const float* b4 = (const float*)d_in[10];
    float* out = (float*)d_out;
    float* ws  = (float*)d_ws;   // uses 64*16*36*4 = 147456 bytes

    dim3 g1(B_ROWS, SLICES);
    fp_pass1<<<g1, TPB, 0, stream>>>(x, cw, ws);
    fp_pass2<<<B_ROWS, 64, 0, stream>>>(ws, cb, w1, b1, w2, b2, w3, b3, w4, b4, out);
}

// Round 3
// 94.112 us; speedup vs baseline: 1.1622x; 1.0129x over previous
//
#include <hip/hip_runtime.h>

// x is (64, 65536) fp32.
#define L_LEN  65536
#define B_ROWS 64
#define NF     32                 // conv filters
#define SLICES 16                 // slices per row (pass-1 grid.y)
#define TPB    256
#define CHUNK  (L_LEN / SLICES)   // 4096 elements per block
#define EPT    (CHUNK / TPB)      // 16 elements per thread
#define NV     36                 // sum, sumsq, max, min, 32 filter maxes
#define COLS   (TPB + 4)          // 260: rows 1040 B -> 16B-aligned, 2-way-free writes

typedef float f2 __attribute__((ext_vector_type(2)));

// -------------------- Pass 1: stats + conv-max partials --------------------
// deep[f] = max_l relu(conv_raw + b[f]) = relu(max_l conv_raw + b[f]);
// bias+relu deferred to pass 2. Conv uses packed fp32 (v_pk_fma_f32):
// outputs (c[2i], c[2i+1]) = w0*{x[2i-1],x[2i]} + w1*{x[2i],x[2i+1]} + w2*{x[2i+1],x[2i+2]}
__global__ __launch_bounds__(TPB) void fp_pass1(
    const float* __restrict__ x, const float* __restrict__ cw,
    float* __restrict__ ws)
{
    const int row   = blockIdx.x;
    const int slice = blockIdx.y;
    const int t     = (int)threadIdx.x;
    const float* xr = x + (size_t)row * L_LEN;
    const int base  = slice * CHUNK + t * EPT;

    // xv[k] = x[base + k - 1]; xv[0]/xv[17] are halo (0 at row edges)
    float xv[EPT + 2];
    const float4* p = reinterpret_cast<const float4*>(xr + base);
    float4 a0 = p[0], a1 = p[1], a2 = p[2], a3 = p[3];
    xv[1]  = a0.x; xv[2]  = a0.y; xv[3]  = a0.z; xv[4]  = a0.w;
    xv[5]  = a1.x; xv[6]  = a1.y; xv[7]  = a1.z; xv[8]  = a1.w;
    xv[9]  = a2.x; xv[10] = a2.y; xv[11] = a2.z; xv[12] = a2.w;
    xv[13] = a3.x; xv[14] = a3.y; xv[15] = a3.z; xv[16] = a3.w;
    xv[0]           = (base == 0)           ? 0.0f : xr[base - 1];
    xv[EPT + 1]     = (base + EPT == L_LEN) ? 0.0f : xr[base + EPT];

    // Packed windows: ev[i] = {xv[2i], xv[2i+1]}, od[i] = {xv[2i+1], xv[2i+2]}
    f2 ev[EPT / 2 + 1], od[EPT / 2];
#pragma unroll
    for (int i = 0; i <= EPT / 2; ++i) ev[i] = f2{xv[2 * i], xv[2 * i + 1]};
#pragma unroll
    for (int i = 0; i < EPT / 2; ++i)  od[i] = f2{xv[2 * i + 1], xv[2 * i + 2]};

    // stats over xv[1..16]
    f2 s2 = f2{0.0f, 0.0f}, ss2 = f2{0.0f, 0.0f};
#pragma unroll
    for (int i = 0; i < EPT / 2; ++i) {
        s2 += od[i];
        ss2 = __builtin_elementwise_fma(od[i], od[i], ss2);
    }
    float s  = s2.x + s2.y;
    float ss = ss2.x + ss2.y;
    float mx = xv[1], mn = xv[1];
#pragma unroll
    for (int j = 2; j <= EPT; ++j) {
        mx = fmaxf(mx, xv[j]);    // folds to v_max3 chains
        mn = fminf(mn, xv[j]);
    }

    // conv-max per filter (raw conv; packed fp32 FMAs + max3 folding)
    float m[NF];
#pragma unroll
    for (int f = 0; f < NF; ++f) {
        const f2 w0 = f2{cw[3 * f + 0], cw[3 * f + 0]};
        const f2 w1 = f2{cw[3 * f + 1], cw[3 * f + 1]};
        const f2 w2 = f2{cw[3 * f + 2], cw[3 * f + 2]};
        float best0 = -3.4e38f, best1 = -3.4e38f;   // two chains for ILP
#pragma unroll
        for (int i = 0; i < EPT / 2; i += 2) {
            f2 c0 = __builtin_elementwise_fma(w0, ev[i],
                     __builtin_elementwise_fma(w1, od[i], w2 * ev[i + 1]));
            f2 c1 = __builtin_elementwise_fma(w0, ev[i + 1],
                     __builtin_elementwise_fma(w1, od[i + 1], w2 * ev[i + 2]));
            best0 = fmaxf(best0, fmaxf(c0.x, c0.y));   // -> v_max3
            best1 = fmaxf(best1, fmaxf(c1.x, c1.y));
        }
        m[f] = fmaxf(best0, best1);
    }

    // ---- block reduction: transposed LDS (value-major), vector reads ----
    __shared__ float mred[NV * COLS];   // 36 * 260 * 4 = 37440 B
    mred[0 * COLS + t] = s;
    mred[1 * COLS + t] = ss;
    mred[2 * COLS + t] = mx;
    mred[3 * COLS + t] = mn;
#pragma unroll
    for (int f = 0; f < NF; ++f) mred[(4 + f) * COLS + t] = m[f];
    __syncthreads();

    if (t < NV * 4) {            // 144 reducers: v = value, g = quarter of columns
        const int v = t >> 2, g = t & 3;
        const float4* p4 = reinterpret_cast<const float4*>(&mred[v * COLS + g * 64]);
        f2 rs2 = f2{0.0f, 0.0f};
        float rmx = -3.4e38f, rmn = 3.4e38f;
#pragma unroll
        for (int k = 0; k < 16; ++k) {
            const float4 q = p4[k];
            rs2 += f2{q.x, q.y};
            rs2 += f2{q.z, q.w};
            rmx = fmaxf(rmx, fmaxf(fmaxf(q.x, q.y), fmaxf(q.z, q.w)));
            rmn = fminf(rmn, fminf(fminf(q.x, q.y), fminf(q.z, q.w)));
        }
        const float rs = rs2.x + rs2.y;
        float r = (v < 2) ? rs : ((v == 3) ? rmn : rmx);
        // combine the 4 quarters (lanes 4v..4v+3 adjacent, never cross wave bound)
        float o = __shfl_xor(r, 1, 64);
        r = (v < 2) ? r + o : ((v == 3) ? fminf(r, o) : fmaxf(r, o));
        o = __shfl_xor(r, 2, 64);
        r = (v < 2) ? r + o : ((v == 3) ? fminf(r, o) : fmaxf(r, o));
        if (g == 0)
            ws[((size_t)(row * SLICES + slice)) * NV + v] = r;
    }
}

// -------------------- Pass 2: slice reduction + MLP --------------------
__global__ __launch_bounds__(64) void fp_pass2(
    const float* __restrict__ ws, const float* __restrict__ cb,
    const float* __restrict__ w1, const float* __restrict__ b1,
    const float* __restrict__ w2, const float* __restrict__ b2,
    const float* __restrict__ w3, const float* __restrict__ b3,
    const float* __restrict__ w4, const float* __restrict__ b4,
    float* __restrict__ out)
{
    const int row = blockIdx.x;
    const int t   = (int)threadIdx.x;
    __shared__ float feat[NV];
    __shared__ float h1[64];
    __shared__ float h2[32];
    __shared__ float h3[16];

    if (t < NV) {
        const float* p = ws + (size_t)row * SLICES * NV + t;
        float rs = 0.0f, rmx = -3.4e38f, rmn = 3.4e38f;
#pragma unroll                       // 16 independent loads -> one latency round
        for (int sl = 0; sl < SLICES; ++sl) {
            const float val = p[sl * NV];
            rs += val;
            rmx = fmaxf(rmx, val);
            rmn = fminf(rmn, val);
        }
        const float r = (t < 2) ? rs : ((t == 3) ? rmn : rmx);
        if (t >= 4)       feat[t - 4] = fmaxf(r + cb[t - 4], 0.0f); // deep
        else if (t == 2)  feat[34] = r;                              // max
        else if (t == 3)  feat[35] = r;                              // min
        else              feat[32 + t] = r;                          // raw sums
    }
    __syncthreads();
    if (t == 0) {
        const float inv  = 1.0f / (float)L_LEN;
        const float mean = feat[32] * inv;
        const float var  = feat[33] * inv - mean * mean;
        feat[32] = mean;
        feat[33] = var;
    }
    __syncthreads();

    // layer 1: (36) -> (64)
    {
        float acc = b1[t];
#pragma unroll
        for (int i = 0; i < NV; ++i) acc = fmaf(feat[i], w1[i * 64 + t], acc);
        h1[t] = fmaxf(acc, 0.0f);
    }
    __syncthreads();
    // layer 2: (64) -> (32)
    if (t < 32) {
        float acc = b2[t];
#pragma unroll
        for (int i = 0; i < 64; ++i) acc = fmaf(h1[i], w2[i * 32 + t], acc);
        h2[t] = fmaxf(acc, 0.0f);
    }
    __syncthreads();
    // layer 3: (32) -> (16)
    if (t < 16) {
        float acc = b3[t];
#pragma unroll
        for (int i = 0; i < 32; ++i) acc = fmaf(h2[i], w3[i * 16 + t], acc);
        h3[t] = fmaxf(acc, 0.0f);
    }
    __syncthreads();
    // layer 4: (16) -> (2)
    if (t < 2) {
        float acc = b4[t];
#pragma unroll
        for (int i = 0; i < 16; ++i) acc = fmaf(h3[i], w4[i * 2 + t], acc);
        out[row * 2 + t] = acc;
    }
}

extern "C" void kernel_launch(void* const* d_in, const int* in_sizes, int n_in,
                              void* d_out, int out_size, void* d_ws, size_t ws_size,
                              hipStream_t stream) {
    const float* x  = (const float*)d_in[0];
    const float* cw = (const float*)d_in[1];
    const float* cb = (const float*)d_in[2];
    const float* w1 = (const float*)d_in[3];
    const float* b1 = (const float*)d_in[4];
    const float* w2 = (const float*)d_in[5];
    const float* b2 = (const float*)d_in[6];
    const float* w3 = (const float*)d_in[7];
    const float* b3 = (const float*)d_in[8];
    const float* w4 = (const float*)d_in[9];
    const float* b4 = (const float*)d_in[10];
    float* out = (float*)d_out;
    float* ws  = (float*)d_ws;   // uses 64*16*36*4 = 147456 bytes

    dim3 g1(B_ROWS, SLICES);
    fp_pass1<<<g1, TPB, 0, stream>>>(x, cw, ws);
    fp_pass2<<<B_ROWS, 64, 0, stream>>>(ws, cb, w1, b1, w2, b2, w3, b3, w4, b4, out);
}